// Round 9
// baseline (81.048 us; speedup 1.0000x reference)
//
#include <hip/hip_runtime.h>
#include <hip/hip_bf16.h>
#include <math.h>

// Problem constants
constexpr int B = 4, S = 4096, N = 16, D = 64, M = 4;
constexpr int SND = S * N * D;      // b stride for q/k/v (floats)
constexpr int ND  = N * D;          // s stride (floats)
constexpr int DD  = D * D;          // 4096
constexpr int NCH = 16;             // k1 chunks per bn
constexpr int SPB = S / NCH;        // 256 s per block (64 per wave)

typedef __attribute__((ext_vector_type(8))) short bf16x8;
typedef __attribute__((ext_vector_type(4))) float f32x4;
typedef unsigned short u16;
typedef unsigned int u32;

__device__ inline u16 f2bf(float x) {
  __hip_bfloat16 h = __float2bfloat16(x);   // RNE
  return __builtin_bit_cast(u16, h);
}

// ---------------------------------------------------------------------------
// Kernel 1: part[bn][ch] = sum_{s in chunk} K[s,:]^T ⊗ V[s,:]  via MFMA.
// k3-CLONE STRUCTURE: no LDS in the hot loop, no barriers in the s-loop,
// free-running waves with ~64 independent dword loads in flight.
// Fragments built in registers: lane (lr,lg), frag element j:
//   A(mi)[j] = bf16(K[s0+8*lg+j][16*mi+lr]),  B(ni)[j] = bf16(V[...][16*ni+lr])
// (identical logical mapping to the round-6-verified LDS layout).
// Each wave: one 64-s window, 2 K=32 steps, 16 MFMA per step, full 64x64 acc.
// Cross-wave sum via 16KB LDS in 4 serial rounds AFTER streaming.
// grid = (64 bn, 16 ch), block = 256 (4 waves) -> 1024 blocks, 16 waves/CU.
// ---------------------------------------------------------------------------
__global__ __launch_bounds__(256, 4) void k1_partials(const float* __restrict__ kg,
                                                      const float* __restrict__ vg,
                                                      float* __restrict__ part) {
  __shared__ float red[DD];          // 16 KB, used only in the epilogue

  const int t = threadIdx.x, w = t >> 6, l = t & 63;
  const int lr = l & 15, lg = (l >> 4) & 3;
  const int bn = blockIdx.x;
  const int b = bn >> 4, n = bn & 15;
  const int ch = blockIdx.y;

  const size_t base = (size_t)b * SND + (size_t)n * D;
  const int s00 = ch * SPB + w * 64;         // this wave's 64-s window

  f32x4 acc[4][4];
#pragma unroll
  for (int i = 0; i < 4; ++i)
#pragma unroll
    for (int j = 0; j < 4; ++j) acc[i][j] = (f32x4)0.f;

#pragma unroll
  for (int st = 0; st < 2; ++st) {
    const int sb = s00 + st * 32 + 8 * lg;   // + j -> s row
    bf16x8 af[4], bv[4];
#pragma unroll
    for (int j = 0; j < 8; ++j) {
      const float* kp = kg + base + (size_t)(sb + j) * ND;
      const float* vp = vg + base + (size_t)(sb + j) * ND;
      const float k0 = kp[lr], k1 = kp[16 + lr], k2 = kp[32 + lr], k3 = kp[48 + lr];
      const float v0 = vp[lr], v1 = vp[16 + lr], v2 = vp[32 + lr], v3 = vp[48 + lr];
      af[0][j] = (short)f2bf(k0);
      af[1][j] = (short)f2bf(k1);
      af[2][j] = (short)f2bf(k2);
      af[3][j] = (short)f2bf(k3);
      bv[0][j] = (short)f2bf(v0);
      bv[1][j] = (short)f2bf(v1);
      bv[2][j] = (short)f2bf(v2);
      bv[3][j] = (short)f2bf(v3);
    }
#pragma unroll
    for (int mi = 0; mi < 4; ++mi)
#pragma unroll
      for (int ni = 0; ni < 4; ++ni)
        acc[mi][ni] = __builtin_amdgcn_mfma_f32_16x16x32_bf16(
            af[mi], bv[ni], acc[mi][ni], 0, 0, 0);
  }

  // ---- epilogue: cross-wave reduction (4 serial rounds, 16 KB LDS) ----
  __syncthreads();
#pragma unroll
  for (int r = 0; r < 4; ++r) {
    if (w == r) {
#pragma unroll
      for (int mi = 0; mi < 4; ++mi)
#pragma unroll
        for (int ni = 0; ni < 4; ++ni)
#pragma unroll
          for (int ri = 0; ri < 4; ++ri) {
            float* dst = &red[(16 * mi + 4 * lg + ri) * 64 + 16 * ni + lr];
            if (r == 0) *dst = acc[mi][ni][ri];
            else        *dst += acc[mi][ni][ri];
          }
    }
    __syncthreads();
  }

  float* p = part + ((size_t)bn * NCH + ch) * DD;
#pragma unroll
  for (int i = 0; i < 4; ++i)
    *(f32x4*)&p[t * 16 + 4 * i] = *(const f32x4*)&red[t * 16 + 4 * i];
}

// ---------------------------------------------------------------------------
// Kernel 2: Meff = sum_m g[m]*sig[m]*memory[b,m,n] + (sum_m g[m](1-sig[m]))*new_info
// Emits bf16 TRANSPOSED meffT[bn][v][k]. grid = (64, 16), block = 256.
// ---------------------------------------------------------------------------
__global__ __launch_bounds__(256) void k2_combine(const float* __restrict__ part,
                                                  const float* __restrict__ memg,
                                                  const float* __restrict__ decay,
                                                  const float* __restrict__ gatew,
                                                  u16* __restrict__ meffT) {
  const int t = threadIdx.x;
  const int bn = blockIdx.x;
  const int b = bn >> 4, n = bn & 15;
  const int kv = blockIdx.y * 256 + t;
  const int k = kv >> 6, v = kv & 63;

  float gw[M], df[M];
#pragma unroll
  for (int m = 0; m < M; ++m) { gw[m] = gatew[m]; df[m] = decay[m]; }
  const float mx = fmaxf(fmaxf(gw[0], gw[1]), fmaxf(gw[2], gw[3]));
  float e[M], esum = 0.f;
#pragma unroll
  for (int m = 0; m < M; ++m) { e[m] = expf(gw[m] - mx); esum += e[m]; }
  float wgt[M], cc = 0.f;
#pragma unroll
  for (int m = 0; m < M; ++m) {
    const float g = e[m] / esum;
    const float sg = 1.f / (1.f + expf(-df[m]));
    wgt[m] = g * sg;
    cc += g * (1.f - sg);
  }

  const float* pb = part + (size_t)bn * NCH * DD + kv;
  float ni = 0.f;
#pragma unroll 8
  for (int ch = 0; ch < NCH; ++ch) ni += pb[(size_t)ch * DD];
  float a = cc * ni;
#pragma unroll
  for (int m = 0; m < M; ++m)
    a += wgt[m] * memg[(((size_t)b * M + m) * N + n) * DD + kv];

  meffT[(size_t)bn * DD + v * 64 + k] = f2bf(a);
}

// ---------------------------------------------------------------------------
// Kernel 3: out[s,v] = q[s,:] @ Meff  via MFMA, LDS-free, free-running.
// grid = (64 bn, 16), block = 256 (4 waves); wave handles 64 s-rows x 64 v.
// ---------------------------------------------------------------------------
__global__ __launch_bounds__(256, 4) void k3_out(const float* __restrict__ qg,
                                                 const u16* __restrict__ meffT,
                                                 float* __restrict__ outg) {
  const int t = threadIdx.x, w = t >> 6, l = t & 63;
  const int lr = l & 15, lg = l >> 4;
  const int bn = blockIdx.x;
  const int b = bn >> 4, n = bn & 15;
  const int s0 = blockIdx.y * 256 + w * 64;

  const u16* mb = meffT + (size_t)bn * DD;
  bf16x8 bfr[4][2];
#pragma unroll
  for (int ni = 0; ni < 4; ++ni)
#pragma unroll
    for (int ks = 0; ks < 2; ++ks)
      bfr[ni][ks] = *(const bf16x8*)(mb + (16 * ni + lr) * 64 + 32 * ks + 8 * lg);

  f32x4 acc[4][4];
#pragma unroll
  for (int i = 0; i < 4; ++i)
#pragma unroll
    for (int j = 0; j < 4; ++j) acc[i][j] = (f32x4)0.f;

  const size_t qbase = (size_t)b * SND + (size_t)n * D;

#pragma unroll
  for (int mi = 0; mi < 4; ++mi) {
    const float* qr = qg + qbase + (size_t)(s0 + 16 * mi + lr) * ND + 8 * lg;
#pragma unroll
    for (int ks = 0; ks < 2; ++ks) {
      float qa[8];
      *(float4*)&qa[0] = *(const float4*)(qr + 32 * ks);
      *(float4*)&qa[4] = *(const float4*)(qr + 32 * ks + 4);
      bf16x8 a;
#pragma unroll
      for (int j = 0; j < 8; ++j) a[j] = (short)f2bf(qa[j]);
#pragma unroll
      for (int ni = 0; ni < 4; ++ni)
        acc[mi][ni] = __builtin_amdgcn_mfma_f32_16x16x32_bf16(a, bfr[ni][ks],
                                                              acc[mi][ni], 0, 0, 0);
    }
  }

#pragma unroll
  for (int mi = 0; mi < 4; ++mi)
#pragma unroll
    for (int ni = 0; ni < 4; ++ni)
#pragma unroll
      for (int ri = 0; ri < 4; ++ri)
        outg[qbase + (size_t)(s0 + 16 * mi + 4 * lg + ri) * ND + 16 * ni + lr] =
            acc[mi][ni][ri];
}

// ---------------------------------------------------------------------------
extern "C" void kernel_launch(void* const* d_in, const int* in_sizes, int n_in,
                              void* d_out, int out_size, void* d_ws, size_t ws_size,
                              hipStream_t stream) {
  const float* q     = (const float*)d_in[0];
  const float* k     = (const float*)d_in[1];
  const float* v     = (const float*)d_in[2];
  const float* memg  = (const float*)d_in[3];
  const float* decay = (const float*)d_in[4];
  const float* gatew = (const float*)d_in[5];
  float* out = (float*)d_out;

  u16* meffT = (u16*)d_ws;                            // 512 KB
  const size_t meffT_bytes = (size_t)64 * DD * sizeof(u16);
  float* part = (float*)((char*)d_ws + meffT_bytes);  // 16 MB (ws >= 17MB proven)

  hipLaunchKernelGGL(k1_partials, dim3(64, NCH), dim3(256), 0, stream,
                     k, v, part);
  hipLaunchKernelGGL(k2_combine, dim3(64, 16), dim3(256), 0, stream,
                     part, memg, decay, gatew, meffT);
  hipLaunchKernelGGL(k3_out, dim3(64, 16), dim3(256), 0, stream,
                     q, meffT, out);
}

// Round 10
// 66.782 us; speedup vs baseline: 1.2136x; 1.2136x over previous
//
#include <hip/hip_runtime.h>
#include <hip/hip_bf16.h>
#include <math.h>

// Problem constants
constexpr int B = 4, S = 4096, N = 16, D = 64, M = 4;
constexpr int SND = S * N * D;      // b stride for q/k/v (floats)
constexpr int ND  = N * D;          // s stride (floats)
constexpr int DD  = D * D;          // 4096
constexpr int NCH = 32;             // k1 chunks per bn
constexpr int SPB = S / NCH;        // 128 s per block (4 stages of 32)

typedef __attribute__((ext_vector_type(8))) short bf16x8;
typedef __attribute__((ext_vector_type(4))) float f32x4;
typedef unsigned short u16;
typedef unsigned int u32;

__device__ inline u16 f2bf(float x) {
  __hip_bfloat16 h = __float2bfloat16(x);   // RNE
  return __builtin_bit_cast(u16, h);
}

// ---------------------------------------------------------------------------
// Kernel 1: part[bn][ch] = sum_{s in chunk} K[s,:]^T ⊗ V[s,:]  via MFMA (bf16).
// Design from r2..r9 post-mortems: maximize lines-in-flight per CU.
//   - 16 KB LDS double-buffer (8 blocks/CU possible, vs 2 at r6/r7's 64 KB)
//   - wave = 16x64 C-strip -> acc is only 16 VGPRs (r9 died with 64-VGPR acc)
//   - 4 independent dwordx4 loads/thread/stage, next stage prefetched (T14)
//   - per load instruction: 4 rows x 256B fully-used cache lines
//   - LDS transpose layout (r6-verified read path): element (d, s) at
//     kT[d][ ((s>>3) ^ ((d>>2)&3))*8 + (s&7) ]  -> frag reads are ds_read_b128,
//     staging writes u32 (s-pairs) at <=4-way bank conflict
// grid = (64 bn, 32 ch), block = 256 (4 waves).
// ---------------------------------------------------------------------------
__global__ __launch_bounds__(256, 5) void k1_partials(const float* __restrict__ kg,
                                                      const float* __restrict__ vg,
                                                      u16* __restrict__ part) {
  __shared__ u16 kT[2][64][32];
  __shared__ u16 vT[2][64][32];

  const int t = threadIdx.x, w = t >> 6, l = t & 63;
  const int lr = l & 15, lg = l >> 4;       // mfma lane coords
  const int rp = 4 * w + (l >> 4);          // staging row-pair 0..15
  const int c  = l & 15;                    // staging d-chunk (4 floats)
  const int bn = blockIdx.x;
  const int b = bn >> 4, n = bn & 15;
  const int ch = blockIdx.y;

  const size_t base = (size_t)b * SND + (size_t)n * D + (size_t)ch * SPB * ND;

  f32x4 acc[4];
#pragma unroll
  for (int i = 0; i < 4; ++i) acc[i] = (f32x4)0.f;

  float kr[2][2][4], vr[2][2][4];           // [reg-set][row-of-pair][4 floats]

#define K1_LOAD(st, sb)                                                     \
  {                                                                         \
    const float* kp = kg + base + (size_t)((st) * 32 + 2 * rp) * ND + 4 * c;\
    const float* vp = vg + base + (size_t)((st) * 32 + 2 * rp) * ND + 4 * c;\
    *(float4*)kr[sb][0] = *(const float4*)kp;                               \
    *(float4*)kr[sb][1] = *(const float4*)(kp + ND);                        \
    *(float4*)vr[sb][0] = *(const float4*)vp;                               \
    *(float4*)vr[sb][1] = *(const float4*)(vp + ND);                        \
  }

#define K1_WRITE(buf, sb)                                                   \
  {                                                                         \
    const int sl = 2 * rp;                                                  \
    _Pragma("unroll") for (int o = 0; o < 4; ++o) {                         \
      const int d = 4 * c + o;                                              \
      const int slot = (((sl >> 3) ^ ((d >> 2) & 3)) << 3) + (sl & 7);      \
      *(u32*)&kT[buf][d][slot] =                                            \
          (u32)f2bf(kr[sb][0][o]) | ((u32)f2bf(kr[sb][1][o]) << 16);        \
      *(u32*)&vT[buf][d][slot] =                                            \
          (u32)f2bf(vr[sb][0][o]) | ((u32)f2bf(vr[sb][1][o]) << 16);        \
    }                                                                       \
  }

#define K1_COMPUTE(buf)                                                     \
  {                                                                         \
    const int grp = (lg ^ (lr >> 2)) << 3;                                  \
    bf16x8 af = *(const bf16x8*)&kT[buf][16 * w + lr][grp];                 \
    bf16x8 bq[4];                                                           \
    _Pragma("unroll") for (int ni = 0; ni < 4; ++ni)                        \
      bq[ni] = *(const bf16x8*)&vT[buf][16 * ni + lr][grp];                 \
    _Pragma("unroll") for (int ni = 0; ni < 4; ++ni)                        \
      acc[ni] = __builtin_amdgcn_mfma_f32_16x16x32_bf16(af, bq[ni],         \
                                                        acc[ni], 0, 0, 0);  \
  }

  // prologue
  K1_LOAD(0, 0);
  K1_WRITE(0, 0);
  K1_LOAD(1, 1);
  __syncthreads();

  // 4 stages of 32 s; one barrier per stage; writes go to the other buffer
#pragma unroll
  for (int st = 0; st < 4; ++st) {
    K1_COMPUTE(st & 1);
    if (st < 3) K1_WRITE((st + 1) & 1, (st + 1) & 1);
    if (st < 2) K1_LOAD(st + 2, st & 1);
    if (st < 3) __syncthreads();
  }

#undef K1_LOAD
#undef K1_WRITE
#undef K1_COMPUTE

  // bf16 partial store: wave w owns C rows 16w..16w+15 (r6-verified mapping)
  u16* p = part + ((size_t)bn * NCH + ch) * DD;
#pragma unroll
  for (int ni = 0; ni < 4; ++ni)
#pragma unroll
    for (int ri = 0; ri < 4; ++ri)
      p[(16 * w + 4 * lg + ri) * 64 + 16 * ni + lr] = f2bf(acc[ni][ri]);
}

// ---------------------------------------------------------------------------
// Kernel 2: Meff = sum_m g[m]*sig[m]*memory[b,m,n] + (sum_m g[m](1-sig[m]))*new_info
// part is bf16 now. Emits bf16 TRANSPOSED meffT[bn][v][k].
// grid = (64, 16), block = 256 — one thread per kv element.
// ---------------------------------------------------------------------------
__global__ __launch_bounds__(256) void k2_combine(const u16* __restrict__ part,
                                                  const float* __restrict__ memg,
                                                  const float* __restrict__ decay,
                                                  const float* __restrict__ gatew,
                                                  u16* __restrict__ meffT) {
  const int t = threadIdx.x;
  const int bn = blockIdx.x;
  const int b = bn >> 4, n = bn & 15;
  const int kv = blockIdx.y * 256 + t;
  const int k = kv >> 6, v = kv & 63;

  float gw[M], df[M];
#pragma unroll
  for (int m = 0; m < M; ++m) { gw[m] = gatew[m]; df[m] = decay[m]; }
  const float mx = fmaxf(fmaxf(gw[0], gw[1]), fmaxf(gw[2], gw[3]));
  float e[M], esum = 0.f;
#pragma unroll
  for (int m = 0; m < M; ++m) { e[m] = expf(gw[m] - mx); esum += e[m]; }
  float wgt[M], cc = 0.f;
#pragma unroll
  for (int m = 0; m < M; ++m) {
    const float g = e[m] / esum;
    const float sg = 1.f / (1.f + expf(-df[m]));
    wgt[m] = g * sg;
    cc += g * (1.f - sg);
  }

  const u16* pb = part + (size_t)bn * NCH * DD + kv;
  float ni = 0.f;
#pragma unroll 8
  for (int ch = 0; ch < NCH; ++ch) {
    __hip_bfloat16 h = __builtin_bit_cast(__hip_bfloat16, pb[(size_t)ch * DD]);
    ni += __bfloat162float(h);
  }
  float a = cc * ni;
#pragma unroll
  for (int m = 0; m < M; ++m)
    a += wgt[m] * memg[(((size_t)b * M + m) * N + n) * DD + kv];

  meffT[(size_t)bn * DD + v * 64 + k] = f2bf(a);
}

// ---------------------------------------------------------------------------
// Kernel 3: out[s,v] = q[s,:] @ Meff  via MFMA, LDS-free, free-running.
// grid = (64 bn, 16), block = 256 (4 waves); wave handles 64 s-rows x 64 v.
// ---------------------------------------------------------------------------
__global__ __launch_bounds__(256, 4) void k3_out(const float* __restrict__ qg,
                                                 const u16* __restrict__ meffT,
                                                 float* __restrict__ outg) {
  const int t = threadIdx.x, w = t >> 6, l = t & 63;
  const int lr = l & 15, lg = l >> 4;
  const int bn = blockIdx.x;
  const int b = bn >> 4, n = bn & 15;
  const int s0 = blockIdx.y * 256 + w * 64;

  const u16* mb = meffT + (size_t)bn * DD;
  bf16x8 bfr[4][2];
#pragma unroll
  for (int ni = 0; ni < 4; ++ni)
#pragma unroll
    for (int ks = 0; ks < 2; ++ks)
      bfr[ni][ks] = *(const bf16x8*)(mb + (16 * ni + lr) * 64 + 32 * ks + 8 * lg);

  f32x4 acc[4][4];
#pragma unroll
  for (int i = 0; i < 4; ++i)
#pragma unroll
    for (int j = 0; j < 4; ++j) acc[i][j] = (f32x4)0.f;

  const size_t qbase = (size_t)b * SND + (size_t)n * D;

#pragma unroll
  for (int mi = 0; mi < 4; ++mi) {
    const float* qr = qg + qbase + (size_t)(s0 + 16 * mi + lr) * ND + 8 * lg;
#pragma unroll
    for (int ks = 0; ks < 2; ++ks) {
      float qa[8];
      *(float4*)&qa[0] = *(const float4*)(qr + 32 * ks);
      *(float4*)&qa[4] = *(const float4*)(qr + 32 * ks + 4);
      bf16x8 a;
#pragma unroll
      for (int j = 0; j < 8; ++j) a[j] = (short)f2bf(qa[j]);
#pragma unroll
      for (int ni = 0; ni < 4; ++ni)
        acc[mi][ni] = __builtin_amdgcn_mfma_f32_16x16x32_bf16(a, bfr[ni][ks],
                                                              acc[mi][ni], 0, 0, 0);
    }
  }

#pragma unroll
  for (int mi = 0; mi < 4; ++mi)
#pragma unroll
    for (int ni = 0; ni < 4; ++ni)
#pragma unroll
      for (int ri = 0; ri < 4; ++ri)
        outg[qbase + (size_t)(s0 + 16 * mi + 4 * lg + ri) * ND + 16 * ni + lr] =
            acc[mi][ni][ri];
}

// ---------------------------------------------------------------------------
extern "C" void kernel_launch(void* const* d_in, const int* in_sizes, int n_in,
                              void* d_out, int out_size, void* d_ws, size_t ws_size,
                              hipStream_t stream) {
  const float* q     = (const float*)d_in[0];
  const float* k     = (const float*)d_in[1];
  const float* v     = (const float*)d_in[2];
  const float* memg  = (const float*)d_in[3];
  const float* decay = (const float*)d_in[4];
  const float* gatew = (const float*)d_in[5];
  float* out = (float*)d_out;

  u16* meffT = (u16*)d_ws;                            // 512 KB
  const size_t meffT_bytes = (size_t)64 * DD * sizeof(u16);
  u16* part = (u16*)((char*)d_ws + meffT_bytes);      // 16 MB bf16 partials

  hipLaunchKernelGGL(k1_partials, dim3(64, NCH), dim3(256), 0, stream,
                     k, v, part);
  hipLaunchKernelGGL(k2_combine, dim3(64, 16), dim3(256), 0, stream,
                     part, memg, decay, gatew, meffT);
  hipLaunchKernelGGL(k3_out, dim3(64, 16), dim3(256), 0, stream,
                     q, meffT, out);
}